// Round 8
// baseline (542.556 us; speedup 1.0000x reference)
//
#include <hip/hip_runtime.h>

#define AW 264   // fp16 elems per activation LDS row (256 + 8 pad)
#define YW 136   // f32 elems per Ys row (128 + 8 pad)

typedef _Float16 f16x8 __attribute__((ext_vector_type(8)));
typedef _Float16 f16x4 __attribute__((ext_vector_type(4)));
typedef __attribute__((ext_vector_type(4))) float f32x4;

// 5-op tanh: 1 - 2/(e^{2x}+1). Safe at +/-inf. |err| ~1e-7.
__device__ __forceinline__ float fast_tanh(float x) {
    float e = __expf(2.0f * x);
    return 1.0f - 2.0f / (e + 1.0f);
}
// Workgroup barrier ordering LDS only — does NOT drain vmcnt, so global
// loads issued before it stay in flight across it.
__device__ __forceinline__ void bar_lds() {
    asm volatile("s_waitcnt lgkmcnt(0)\n\ts_barrier" ::: "memory");
}

// ---------------- fused precompute: weights -> MFMA fragment layout, hi/lo fp16 ----
// F layout: [plane][nt][kc][lane(64)][j(8)]; value = W[n*K+k], n=nt*16+(l&15),
// k=kc*32+(l>>4)*8+j. (Identical lane formula serves as A- or B-operand.)
__global__ __launch_bounds__(256) void pk_all(
    const float* __restrict__ Wvf1, const float* __restrict__ Wvf2,
    const float* __restrict__ Wm,   const float* __restrict__ bm,
    const float* __restrict__ logsig,
    _Float16* __restrict__ W1F, _Float16* __restrict__ W2F,
    _Float16* __restrict__ A3F, float* __restrict__ c_all)
{
    __shared__ float ls[32][62];
    const int b = blockIdx.x, t = threadIdx.x;
    if (b < 128) {                      // W1: N=256 x K=128 (16 nt, 4 kc)
        int u = b * 256 + t;            // 32768 per plane
        int j = u & 7, l = (u >> 3) & 63;
        int kc = (u >> 9) & 3, nt = (u >> 9) >> 2;
        int n = nt * 16 + (l & 15), k = kc * 32 + (l >> 4) * 8 + j;
        float w = Wvf1[n * 128 + k];
        _Float16 hi = (_Float16)w;
        W1F[u] = hi;
        W1F[32768 + u] = (_Float16)(w - (float)hi);
    } else if (b < 384) {               // W2: 256x256 (16 nt, 8 kc)
        int u = (b - 128) * 256 + t;    // 65536 per plane
        int j = u & 7, l = (u >> 3) & 63;
        int kc = (u >> 9) & 7, nt = (u >> 9) >> 3;
        int n = nt * 16 + (l & 15), k = kc * 32 + (l >> 4) * 8 + j;
        float w = Wvf2[n * 256 + k];
        _Float16 hi = (_Float16)w;
        W2F[u] = hi;
        W2F[65536 + u] = (_Float16)(w - (float)hi);
    } else if (b < 896) {               // A_r[h,v], r-chunks of 8 (4 chunks x 128 blocks)
        for (int e = t; e < 32 * 62; e += 256)
            ls[e / 62][e % 62] = logsig[(e / 62) * 63 + 1 + (e % 62)];
        __syncthreads();
        int idx = b - 384;
        int chunk = idx >> 7;           // 0..3 -> r in [chunk*8, chunk*8+8)
        int u = (idx & 127) * 256 + t;  // 32768 per plane per r (8 nt, 8 kc)
        int j = u & 7, l = (u >> 3) & 63, kc = (u >> 9) & 7, nt = (u >> 12) & 7;
        int h = nt * 16 + (l & 15);
        int v = kc * 32 + (l >> 4) * 8 + j;
        int r0 = chunk * 8;
        float acc[8];
#pragma unroll
        for (int r = 0; r < 8; r++) acc[r] = 0.f;
        for (int ll = 0; ll < 62; ll++) {
            float wv = Wm[(h * 62 + ll) * 256 + v];
#pragma unroll
            for (int r = 0; r < 8; r++) acc[r] += wv * ls[r0 + r][ll];
        }
        for (int r = 0; r < 8; r++) {
            _Float16 hi = (_Float16)acc[r];
            A3F[(r0 + r) * 65536 + u] = hi;
            A3F[(r0 + r) * 65536 + 32768 + u] = (_Float16)(acc[r] - (float)hi);
        }
    } else {                            // c_r[h] = bm[h,:] . seg_r
        int u = (b - 896) * 256 + t;    // 4096 = [r(32)][h(128)]
        int r = u >> 7, h = u & 127;
        float acc = 0.f;
        for (int ll = 0; ll < 62; ll++) acc += bm[h * 62 + ll] * logsig[r * 63 + 1 + ll];
        c_all[u] = acc;
    }
}

// ---------------- main fused kernel: 32 blocks x 16 rows, 4 waves, 20-step Heun ---
// Transposed MFMA form: weights = A-operand, activations = B-operand
// -> D[row=q*4+reg = out-neuron][col=lane&15 = batch row]: commits are 4
// consecutive cols => packed ds_write_b64. 4 waves x 4 n-tiles halves the
// LDS read duplication vs 8x2. fp16 hi/lo both operands, 3 MFMA chains.
__global__ __launch_bounds__(256, 1) void rde_main(
    const float* __restrict__ ts, const float* __restrict__ x0,
    const float* __restrict__ intervals,
    const float* __restrict__ b1g, const float* __restrict__ b2g,
    const float* __restrict__ Win, const float* __restrict__ bin,
    const float* __restrict__ Wout, const float* __restrict__ bout,
    const _Float16* __restrict__ W1F, const _Float16* __restrict__ W2F,
    const _Float16* __restrict__ A3F, const float* __restrict__ c_all,
    float* __restrict__ out)
{
    __shared__ __align__(16) _Float16 P0h[16 * AW], P0l[16 * AW];
    __shared__ __align__(16) _Float16 P1h[16 * AW], P1l[16 * AW];
    __shared__ float Ys[16 * YW];
    __shared__ float ivl[33];
    __shared__ int   r_arr[40];
    __shared__ float s_arr[40];
    __shared__ float lg[16][12];

    const int t    = threadIdx.x;
    const int lane = t & 63;
    const int w    = t >> 6;        // wave 0..3
    const int m16  = lane & 15;     // batch row within tile
    const int q    = lane >> 4;
    const int row0 = blockIdx.x * 16;

    if (t < 33) ivl[t] = intervals[t];
    __syncthreads();

    const float ts0 = ts[0];
    const float dt  = __fdiv_rn(ts[32] - ts0, 20.0f);   // bit-exact vs reference

    if (t < 40) {   // searchsorted idx + 1/delta for all 40 VF evals
        int i = t >> 1;
        float tv = ts0 + (float)i * dt;
        if (t & 1) tv += dt;
        int p = 0;
        for (int j2 = 0; j2 < 32; j2++) p += (ivl[1 + j2] < tv) ? 1 : 0;
        int idx = p + 1;
        idx = idx < 1 ? 1 : idx;
        idx = idx > 32 ? 32 : idx;
        r_arr[t] = idx - 1;
        s_arr[t] = __fdiv_rn(1.0f, ivl[idx] - ivl[idx - 1]);
    }

    // biases: transposed form -> bias varies along D rows (q*4+r), 4 consecutive
    f32x4 b1f[4], b2f[4];
#pragma unroll
    for (int tt = 0; tt < 4; tt++) {
        b1f[tt] = *(const f32x4*)(b1g + (w * 4 + tt) * 16 + q * 4);
        b2f[tt] = *(const f32x4*)(b2g + (w * 4 + tt) * 16 + q * 4);
    }

    // y0 = x0 @ Win.T + bin -> Y regs: Y[tt][r] = y[m16][(w*2+tt)*16+q*4+r]
    float Y[2][4], K1[2][4];
    {
        const float* xr = x0 + (row0 + m16) * 5;
        float xv[5];
#pragma unroll
        for (int d = 0; d < 5; d++) xv[d] = xr[d];
#pragma unroll
        for (int tt = 0; tt < 2; tt++) {
            int h0 = (w * 2 + tt) * 16 + q * 4;
            f16x4 hv, lv;
#pragma unroll
            for (int r = 0; r < 4; r++) {
                float acc = bin[h0 + r];
#pragma unroll
                for (int d = 0; d < 5; d++) acc += xv[d] * Win[(h0 + r) * 5 + d];
                Y[tt][r] = acc;
                K1[tt][r] = 0.f;
                _Float16 hi = (_Float16)acc;
                hv[r] = hi;
                lv[r] = (_Float16)(acc - (float)hi);
            }
            *(f16x4*)(P0h + m16 * AW + h0) = hv;
            *(f16x4*)(P0l + m16 * AW + h0) = lv;
        }
    }
    __syncthreads();

    // initial W1 window A (n-tiles w*4+0, w*4+1)
    f16x8 w1a[2][4][2];
#pragma unroll
    for (int tt = 0; tt < 2; tt++)
#pragma unroll
        for (int kc = 0; kc < 4; kc++) {
            const _Float16* bp = W1F + ((w * 4 + tt) * 4 + kc) * 512 + lane * 8;
            w1a[tt][kc][0] = *(const f16x8*)bp;
            w1a[tt][kc][1] = *(const f16x8*)(bp + 32768);
        }

    _Float16 *Aih = P0h, *Ail = P0l;
    _Float16 *Aoh = P1h, *Aol = P1l;

#pragma unroll 1
    for (int e = 0; e < 40; e++) {
        const int half = e & 1;
        const int ri   = r_arr[e];
        const float s  = s_arr[e];
        const _Float16* ABase = A3F + ri * 65536;

        // ================= stage1: h1 = relu(W1 . y), K=128 =================
        f16x8 w1b[2][4][2];                     // issue n-tiles w*4+2, w*4+3
#pragma unroll
        for (int tt = 0; tt < 2; tt++)
#pragma unroll
            for (int kc = 0; kc < 4; kc++) {
                const _Float16* bp = W1F + ((w * 4 + 2 + tt) * 4 + kc) * 512 + lane * 8;
                w1b[tt][kc][0] = *(const f16x8*)bp;
                w1b[tt][kc][1] = *(const f16x8*)(bp + 32768);
            }
        f16x8 yh[4], yl[4];                     // act fragments (B-operand)
#pragma unroll
        for (int kc = 0; kc < 4; kc++) {
            int ao = m16 * AW + kc * 32 + q * 8;
            yh[kc] = *(const f16x8*)(Aih + ao);
            yl[kc] = *(const f16x8*)(Ail + ao);
        }
        f32x4 aA[4], aB[4], aC[4];
#pragma unroll
        for (int tt = 0; tt < 4; tt++) {
            aA[tt] = b1f[tt];
            aB[tt] = (f32x4){0.f, 0.f, 0.f, 0.f};
            aC[tt] = (f32x4){0.f, 0.f, 0.f, 0.f};
        }
#pragma unroll
        for (int tt = 0; tt < 2; tt++)
#pragma unroll
            for (int kc = 0; kc < 4; kc++) {
                aA[tt] = __builtin_amdgcn_mfma_f32_16x16x32_f16(w1a[tt][kc][0], yh[kc], aA[tt], 0, 0, 0);
                aB[tt] = __builtin_amdgcn_mfma_f32_16x16x32_f16(w1a[tt][kc][1], yh[kc], aB[tt], 0, 0, 0);
                aC[tt] = __builtin_amdgcn_mfma_f32_16x16x32_f16(w1a[tt][kc][0], yl[kc], aC[tt], 0, 0, 0);
            }
#pragma unroll
        for (int tt = 0; tt < 2; tt++)
#pragma unroll
            for (int kc = 0; kc < 4; kc++) {
                aA[2+tt] = __builtin_amdgcn_mfma_f32_16x16x32_f16(w1b[tt][kc][0], yh[kc], aA[2+tt], 0, 0, 0);
                aB[2+tt] = __builtin_amdgcn_mfma_f32_16x16x32_f16(w1b[tt][kc][1], yh[kc], aB[2+tt], 0, 0, 0);
                aC[2+tt] = __builtin_amdgcn_mfma_f32_16x16x32_f16(w1b[tt][kc][0], yl[kc], aC[2+tt], 0, 0, 0);
            }
        // issue W2 window 0 (kc 0,1)
        f16x8 w20[2][4][2];
#pragma unroll
        for (int kk = 0; kk < 2; kk++)
#pragma unroll
            for (int tt = 0; tt < 4; tt++) {
                const _Float16* bp = W2F + ((w * 4 + tt) * 8 + kk) * 512 + lane * 8;
                w20[kk][tt][0] = *(const f16x8*)bp;
                w20[kk][tt][1] = *(const f16x8*)(bp + 65536);
            }
#pragma unroll
        for (int tt = 0; tt < 4; tt++) {        // commit h1 -> Aout (b64 hi + b64 lo)
            int n0 = (w * 4 + tt) * 16 + q * 4;
            f16x4 hv, lv;
#pragma unroll
            for (int r = 0; r < 4; r++) {
                float v = fmaxf(aA[tt][r] + aB[tt][r] + aC[tt][r], 0.f);
                _Float16 hi = (_Float16)v;
                hv[r] = hi;
                lv[r] = (_Float16)(v - (float)hi);
            }
            *(f16x4*)(Aoh + m16 * AW + n0) = hv;
            *(f16x4*)(Aol + m16 * AW + n0) = lv;
        }
        bar_lds();

        // ================= stage2: h2 = tanh(W2 . h1), K=256 =================
        f16x8 w21[2][4][2];                     // kc 2,3
#pragma unroll
        for (int kk = 0; kk < 2; kk++)
#pragma unroll
            for (int tt = 0; tt < 4; tt++) {
                const _Float16* bp = W2F + ((w * 4 + tt) * 8 + 2 + kk) * 512 + lane * 8;
                w21[kk][tt][0] = *(const f16x8*)bp;
                w21[kk][tt][1] = *(const f16x8*)(bp + 65536);
            }
#pragma unroll
        for (int tt = 0; tt < 4; tt++) {
            aA[tt] = b2f[tt];
            aB[tt] = (f32x4){0.f, 0.f, 0.f, 0.f};
            aC[tt] = (f32x4){0.f, 0.f, 0.f, 0.f};
        }
#pragma unroll
        for (int kk = 0; kk < 2; kk++) {        // kc 0,1 with w20
            int ao = m16 * AW + kk * 32 + q * 8;
            f16x8 ah = *(const f16x8*)(Aoh + ao);
            f16x8 al = *(const f16x8*)(Aol + ao);
#pragma unroll
            for (int tt = 0; tt < 4; tt++) {
                aA[tt] = __builtin_amdgcn_mfma_f32_16x16x32_f16(w20[kk][tt][0], ah, aA[tt], 0, 0, 0);
                aB[tt] = __builtin_amdgcn_mfma_f32_16x16x32_f16(w20[kk][tt][1], ah, aB[tt], 0, 0, 0);
                aC[tt] = __builtin_amdgcn_mfma_f32_16x16x32_f16(w20[kk][tt][0], al, aC[tt], 0, 0, 0);
            }
        }
        f16x8 w22[2][4][2];                     // kc 4,5
#pragma unroll
        for (int kk = 0; kk < 2; kk++)
#pragma unroll
            for (int tt = 0; tt < 4; tt++) {
                const _Float16* bp = W2F + ((w * 4 + tt) * 8 + 4 + kk) * 512 + lane * 8;
                w22[kk][tt][0] = *(const f16x8*)bp;
                w22[kk][tt][1] = *(const f16x8*)(bp + 65536);
            }
#pragma unroll
        for (int kk = 0; kk < 2; kk++) {        // kc 2,3 with w21
            int ao = m16 * AW + (2 + kk) * 32 + q * 8;
            f16x8 ah = *(const f16x8*)(Aoh + ao);
            f16x8 al = *(const f16x8*)(Aol + ao);
#pragma unroll
            for (int tt = 0; tt < 4; tt++) {
                aA[tt] = __builtin_amdgcn_mfma_f32_16x16x32_f16(w21[kk][tt][0], ah, aA[tt], 0, 0, 0);
                aB[tt] = __builtin_amdgcn_mfma_f32_16x16x32_f16(w21[kk][tt][1], ah, aB[tt], 0, 0, 0);
                aC[tt] = __builtin_amdgcn_mfma_f32_16x16x32_f16(w21[kk][tt][0], al, aC[tt], 0, 0, 0);
            }
        }
        f16x8 w23[2][4][2];                     // kc 6,7
#pragma unroll
        for (int kk = 0; kk < 2; kk++)
#pragma unroll
            for (int tt = 0; tt < 4; tt++) {
                const _Float16* bp = W2F + ((w * 4 + tt) * 8 + 6 + kk) * 512 + lane * 8;
                w23[kk][tt][0] = *(const f16x8*)bp;
                w23[kk][tt][1] = *(const f16x8*)(bp + 65536);
            }
#pragma unroll
        for (int kk = 0; kk < 2; kk++) {        // kc 4,5 with w22
            int ao = m16 * AW + (4 + kk) * 32 + q * 8;
            f16x8 ah = *(const f16x8*)(Aoh + ao);
            f16x8 al = *(const f16x8*)(Aol + ao);
#pragma unroll
            for (int tt = 0; tt < 4; tt++) {
                aA[tt] = __builtin_amdgcn_mfma_f32_16x16x32_f16(w22[kk][tt][0], ah, aA[tt], 0, 0, 0);
                aB[tt] = __builtin_amdgcn_mfma_f32_16x16x32_f16(w22[kk][tt][1], ah, aB[tt], 0, 0, 0);
                aC[tt] = __builtin_amdgcn_mfma_f32_16x16x32_f16(w22[kk][tt][0], al, aC[tt], 0, 0, 0);
            }
        }
        // issue A_r window 0 (kc 0..3, n-tiles w*2, w*2+1) + c vector
        f16x8 a30[4][2][2];
#pragma unroll
        for (int kc = 0; kc < 4; kc++)
#pragma unroll
            for (int tt = 0; tt < 2; tt++) {
                const _Float16* bp = ABase + ((w * 2 + tt) * 8 + kc) * 512 + lane * 8;
                a30[kc][tt][0] = *(const f16x8*)bp;
                a30[kc][tt][1] = *(const f16x8*)(bp + 32768);
            }
        f32x4 cf[2];
#pragma unroll
        for (int tt = 0; tt < 2; tt++)
            cf[tt] = *(const f32x4*)(c_all + ri * 128 + (w * 2 + tt) * 16 + q * 4);
#pragma unroll
        for (int kk = 0; kk < 2; kk++) {        // kc 6,7 with w23
            int ao = m16 * AW + (6 + kk) * 32 + q * 8;
            f16x8 ah = *(const f16x8*)(Aoh + ao);
            f16x8 al = *(const f16x8*)(Aol + ao);
#pragma unroll
            for (int tt = 0; tt < 4; tt++) {
                aA[tt] = __builtin_amdgcn_mfma_f32_16x16x32_f16(w23[kk][tt][0], ah, aA[tt], 0, 0, 0);
                aB[tt] = __builtin_amdgcn_mfma_f32_16x16x32_f16(w23[kk][tt][1], ah, aB[tt], 0, 0, 0);
                aC[tt] = __builtin_amdgcn_mfma_f32_16x16x32_f16(w23[kk][tt][0], al, aC[tt], 0, 0, 0);
            }
        }
#pragma unroll
        for (int tt = 0; tt < 4; tt++) {        // commit h2 (tanh) -> Ain
            int n0 = (w * 4 + tt) * 16 + q * 4;
            f16x4 hv, lv;
#pragma unroll
            for (int r = 0; r < 4; r++) {
                float v = fast_tanh(aA[tt][r] + aB[tt][r] + aC[tt][r]);
                _Float16 hi = (_Float16)v;
                hv[r] = hi;
                lv[r] = (_Float16)(v - (float)hi);
            }
            *(f16x4*)(Aih + m16 * AW + n0) = hv;
            *(f16x4*)(Ail + m16 * AW + n0) = lv;
        }
        bar_lds();

        // ================= stage3: k = (A_r . h2 + c) * s =================
        f16x8 a31[4][2][2];                     // kc 4..7
#pragma unroll
        for (int kc = 0; kc < 4; kc++)
#pragma unroll
            for (int tt = 0; tt < 2; tt++) {
                const _Float16* bp = ABase + ((w * 2 + tt) * 8 + 4 + kc) * 512 + lane * 8;
                a31[kc][tt][0] = *(const f16x8*)bp;
                a31[kc][tt][1] = *(const f16x8*)(bp + 32768);
            }
        f32x4 kA[2], kB[2], kC[2];
#pragma unroll
        for (int tt = 0; tt < 2; tt++) {
            kA[tt] = cf[tt];
            kB[tt] = (f32x4){0.f, 0.f, 0.f, 0.f};
            kC[tt] = (f32x4){0.f, 0.f, 0.f, 0.f};
        }
#pragma unroll
        for (int kc = 0; kc < 4; kc++) {        // kc 0..3 with a30
            int ao = m16 * AW + kc * 32 + q * 8;
            f16x8 ah = *(const f16x8*)(Aih + ao);
            f16x8 al = *(const f16x8*)(Ail + ao);
#pragma unroll
            for (int tt = 0; tt < 2; tt++) {
                kA[tt] = __builtin_amdgcn_mfma_f32_16x16x32_f16(a30[kc][tt][0], ah, kA[tt], 0, 0, 0);
                kB[tt] = __builtin_amdgcn_mfma_f32_16x16x32_f16(a30[kc][tt][1], ah, kB[tt], 0, 0, 0);
                kC[tt] = __builtin_amdgcn_mfma_f32_16x16x32_f16(a30[kc][tt][0], al, kC[tt], 0, 0, 0);
            }
        }
#pragma unroll
        for (int tt = 0; tt < 2; tt++)          // prefetch next-eval W1 window A
#pragma unroll
            for (int kc = 0; kc < 4; kc++) {
                const _Float16* bp = W1F + ((w * 4 + tt) * 4 + kc) * 512 + lane * 8;
                w1a[tt][kc][0] = *(const f16x8*)bp;
                w1a[tt][kc][1] = *(const f16x8*)(bp + 32768);
            }
#pragma unroll
        for (int kc = 0; kc < 4; kc++) {        // kc 4..7 with a31
            int ao = m16 * AW + (4 + kc) * 32 + q * 8;
            f16x8 ah = *(const f16x8*)(Aih + ao);
            f16x8 al = *(const f16x8*)(Ail + ao);
#pragma unroll
            for (int tt = 0; tt < 2; tt++) {
                kA[tt] = __builtin_amdgcn_mfma_f32_16x16x32_f16(a31[kc][tt][0], ah, kA[tt], 0, 0, 0);
                kB[tt] = __builtin_amdgcn_mfma_f32_16x16x32_f16(a31[kc][tt][1], ah, kB[tt], 0, 0, 0);
                kC[tt] = __builtin_amdgcn_mfma_f32_16x16x32_f16(a31[kc][tt][0], al, kC[tt], 0, 0, 0);
            }
        }
#pragma unroll
        for (int tt = 0; tt < 2; tt++) {        // Heun commit + y -> Aout
            int h0 = (w * 2 + tt) * 16 + q * 4;
            f16x4 hv, lv;
#pragma unroll
            for (int r = 0; r < 4; r++) {
                float kv = (kA[tt][r] + kB[tt][r] + kC[tt][r]) * s;
                float yn;
                if (half == 0) {                 // k1: stash, form y+dt*k1
                    K1[tt][r] = kv;
                    yn = Y[tt][r] + dt * kv;
                } else {                         // k2: y += 0.5*dt*(k1+k2)
                    yn = Y[tt][r] + 0.5f * dt * (K1[tt][r] + kv);
                    Y[tt][r] = yn;
                }
                _Float16 hi = (_Float16)yn;
                hv[r] = hi;
                lv[r] = (_Float16)(yn - (float)hi);
            }
            *(f16x4*)(Aoh + m16 * AW + h0) = hv;
            *(f16x4*)(Aol + m16 * AW + h0) = lv;
        }
        bar_lds();
        _Float16* tp;
        tp = Aih; Aih = Aoh; Aoh = tp;
        tp = Ail; Ail = Aol; Aol = tp;
    }

    // epilogue: Y regs -> Ys f32 [m][h]
#pragma unroll
    for (int tt = 0; tt < 2; tt++)
#pragma unroll
        for (int r = 0; r < 4; r++)
            Ys[m16 * YW + (w * 2 + tt) * 16 + q * 4 + r] = Y[tt][r];
    __syncthreads();
    if (t < 160) {                  // logits
        int m = t / 10, c = t % 10;
        float acc = bout[c];
        for (int k = 0; k < 128; k++) acc += Ys[m * YW + k] * Wout[c * 128 + k];
        lg[m][c] = acc;
    }
    __syncthreads();
    if (t < 16) {                   // softmax
        float mx = -1e30f;
#pragma unroll
        for (int c = 0; c < 10; c++) mx = fmaxf(mx, lg[t][c]);
        float ex[10], sum = 0.f;
#pragma unroll
        for (int c = 0; c < 10; c++) { ex[c] = expf(lg[t][c] - mx); sum += ex[c]; }
        float inv = __fdiv_rn(1.0f, sum);
#pragma unroll
        for (int c = 0; c < 10; c++) out[(row0 + t) * 10 + c] = ex[c] * inv;
    }
}

extern "C" void kernel_launch(void* const* d_in, const int* in_sizes, int n_in,
                              void* d_out, int out_size, void* d_ws, size_t ws_size,
                              hipStream_t stream) {
    const float* ts     = (const float*)d_in[0];
    const float* logsig = (const float*)d_in[1];
    const float* x0     = (const float*)d_in[2];
    const float* ivls   = (const float*)d_in[3];
    const float* Wvf1   = (const float*)d_in[4];
    const float* bvf1   = (const float*)d_in[5];
    const float* Wvf2   = (const float*)d_in[6];
    const float* bvf2   = (const float*)d_in[7];
    const float* Wm     = (const float*)d_in[8];
    const float* bm     = (const float*)d_in[9];
    const float* Win    = (const float*)d_in[10];
    const float* bin    = (const float*)d_in[11];
    const float* Wout   = (const float*)d_in[12];
    const float* bout   = (const float*)d_in[13];

    _Float16* W1F = (_Float16*)d_ws;            // 65536 halfs (128KB, hi+lo)
    _Float16* W2F = W1F + 65536;                // 131072 halfs (256KB, hi+lo)
    _Float16* A3F = W2F + 131072;               // 32*65536 halfs (4MB, hi+lo per r)
    float* c_all = (float*)(A3F + 32 * 65536);  // 4096 f32 (16KB)
    float* out = (float*)d_out;

    pk_all<<<dim3(912), dim3(256), 0, stream>>>(Wvf1, Wvf2, Wm, bm, logsig,
                                                W1F, W2F, A3F, c_all);
    rde_main<<<dim3(32), dim3(256), 0, stream>>>(
        ts, x0, ivls, bvf1, bvf2, Win, bin, Wout, bout,
        W1F, W2F, A3F, c_all, out);
}

// Round 9
// 316.944 us; speedup vs baseline: 1.7118x; 1.7118x over previous
//
#include <hip/hip_runtime.h>

#define AW 264   // fp16 elems per activation LDS row (256 + 8 pad)
#define YW 136   // f32 elems per Ys row (128 + 8 pad)

typedef _Float16 f16x8 __attribute__((ext_vector_type(8)));
typedef _Float16 f16x4 __attribute__((ext_vector_type(4)));
typedef __attribute__((ext_vector_type(4))) float f32x4;

// 5-op tanh: 1 - 2/(e^{2x}+1). Safe at +/-inf. |err| ~1e-7.
__device__ __forceinline__ float fast_tanh(float x) {
    float e = __expf(2.0f * x);
    return 1.0f - 2.0f / (e + 1.0f);
}
// Workgroup barrier ordering LDS only — does NOT drain vmcnt, so global
// loads issued before it stay in flight across it.
__device__ __forceinline__ void bar_lds() {
    asm volatile("s_waitcnt lgkmcnt(0)\n\ts_barrier" ::: "memory");
}

// ---------------- fused precompute: weights -> MFMA fragment layout, hi/lo fp16 ----
// F layout: [plane][nt][kc][lane(64)][j(8)]; value = W[n*K+k], n=nt*16+(l&15),
// k=kc*32+(l>>4)*8+j. Same lane formula serves as A- or B-operand fragment.
__global__ __launch_bounds__(256) void pk_all(
    const float* __restrict__ Wvf1, const float* __restrict__ Wvf2,
    const float* __restrict__ Wm,   const float* __restrict__ bm,
    const float* __restrict__ logsig,
    _Float16* __restrict__ W1F, _Float16* __restrict__ W2F,
    _Float16* __restrict__ A3F, float* __restrict__ c_all)
{
    __shared__ float ls[32][62];
    __shared__ float sW[16][62][33];    // 16 h x 62 l x 32 v (+1 pad) = 131 KB
    const int b = blockIdx.x, t = threadIdx.x;
    if (b < 128) {                      // W1: N=256 x K=128 (16 nt, 4 kc)
        int u = b * 256 + t;            // 32768 per plane
        int j = u & 7, l = (u >> 3) & 63;
        int kc = (u >> 9) & 3, nt = (u >> 9) >> 2;
        int n = nt * 16 + (l & 15), k = kc * 32 + (l >> 4) * 8 + j;
        float w = Wvf1[n * 128 + k];
        _Float16 hi = (_Float16)w;
        W1F[u] = hi;
        W1F[32768 + u] = (_Float16)(w - (float)hi);
    } else if (b < 384) {               // W2: 256x256 (16 nt, 8 kc)
        int u = (b - 128) * 256 + t;    // 65536 per plane
        int j = u & 7, l = (u >> 3) & 63;
        int kc = (u >> 9) & 7, nt = (u >> 9) >> 3;
        int n = nt * 16 + (l & 15), k = kc * 32 + (l >> 4) * 8 + j;
        float w = Wvf2[n * 256 + k];
        _Float16 hi = (_Float16)w;
        W2F[u] = hi;
        W2F[65536 + u] = (_Float16)(w - (float)hi);
    } else if (b < 448) {               // A_r: 64 blocks, one (nt,kc), all 32 r's
        int nt = (b - 384) >> 3, kc = (b - 384) & 7;
        for (int e2 = t; e2 < 32 * 62; e2 += 256)
            ls[e2 / 62][e2 % 62] = logsig[(e2 / 62) * 63 + 1 + (e2 % 62)];
        // stage Wm tile coalesced: 992 rows (h,l) x 32 consecutive v (128 B runs)
        for (int row = t >> 5; row < 992; row += 8) {
            int hl = row / 62, ll = row % 62, c = t & 31;
            sW[hl][ll][c] = Wm[((nt * 16 + hl) * 62 + ll) * 256 + kc * 32 + c];
        }
        __syncthreads();
        // 2 frag elements per thread: elem0=t, elem1=t+256 (elem = l*8+j)
        int lane0 = t >> 3, j0 = t & 7;
        int hl0 = lane0 & 15, vl0 = (lane0 >> 4) * 8 + j0;
        int lane1 = lane0 + 32;
        int hl1 = lane1 & 15, vl1 = (lane1 >> 4) * 8 + j0;
        float acc0[32], acc1[32];
#pragma unroll
        for (int r = 0; r < 32; r++) { acc0[r] = 0.f; acc1[r] = 0.f; }
        for (int ll = 0; ll < 62; ll++) {
            float w0 = sW[hl0][ll][vl0];
            float w1 = sW[hl1][ll][vl1];
#pragma unroll
            for (int r = 0; r < 32; r++) {
                float lv = ls[r][ll];
                acc0[r] += w0 * lv;
                acc1[r] += w1 * lv;
            }
        }
        int ub = (nt * 8 + kc) * 512;
        for (int r = 0; r < 32; r++) {
            _Float16 h0 = (_Float16)acc0[r];
            A3F[r * 65536 + ub + t] = h0;
            A3F[r * 65536 + 32768 + ub + t] = (_Float16)(acc0[r] - (float)h0);
            _Float16 h1 = (_Float16)acc1[r];
            A3F[r * 65536 + ub + 256 + t] = h1;
            A3F[r * 65536 + 32768 + ub + 256 + t] = (_Float16)(acc1[r] - (float)h1);
        }
    } else {                            // c_r[h] = bm[h,:] . seg_r
        int u = (b - 448) * 256 + t;    // 4096 = [r(32)][h(128)]
        int r = u >> 7, h = u & 127;
        float acc = 0.f;
        for (int ll = 0; ll < 62; ll++) acc += bm[h * 62 + ll] * logsig[r * 63 + 1 + ll];
        c_all[u] = acc;
    }
}

// ---------------- main fused kernel: 32 blocks x 16 rows, 8 waves, 20-step Heun ---
// Round-7 streaming structure (512 thr, 2 waves/SIMD, <=64-VGPR weight windows,
// bar_lds keeps loads in flight) + transposed MFMA (weights = A-operand) so
// D rows = output neurons -> packed f16x4 (b64) commits instead of u16 scatter.
// fp16 hi/lo both operands, 3 MFMA chains (validated absmax 0.0039).
__global__ __launch_bounds__(512, 2) void rde_main(
    const float* __restrict__ ts, const float* __restrict__ x0,
    const float* __restrict__ intervals,
    const float* __restrict__ b1g, const float* __restrict__ b2g,
    const float* __restrict__ Win, const float* __restrict__ bin,
    const float* __restrict__ Wout, const float* __restrict__ bout,
    const _Float16* __restrict__ W1F, const _Float16* __restrict__ W2F,
    const _Float16* __restrict__ A3F, const float* __restrict__ c_all,
    float* __restrict__ out)
{
    __shared__ __align__(16) _Float16 P0h[16 * AW], P0l[16 * AW];
    __shared__ __align__(16) _Float16 P1h[16 * AW], P1l[16 * AW];
    __shared__ float Ys[16 * YW];
    __shared__ float ivl[33];
    __shared__ int   r_arr[40];
    __shared__ float s_arr[40];
    __shared__ float lg[16][12];

    const int t    = threadIdx.x;
    const int lane = t & 63;
    const int wv   = t >> 6;        // wave 0..7
    const int m16  = lane & 15;     // batch row within tile
    const int q    = lane >> 4;
    const int row0 = blockIdx.x * 16;

    if (t < 33) ivl[t] = intervals[t];
    __syncthreads();

    const float ts0 = ts[0];
    const float dt  = __fdiv_rn(ts[32] - ts0, 20.0f);   // bit-exact vs reference

    if (t < 40) {   // searchsorted idx + 1/delta for all 40 VF evals
        int i = t >> 1;
        float tv = ts0 + (float)i * dt;
        if (t & 1) tv += dt;
        int p = 0;
        for (int j2 = 0; j2 < 32; j2++) p += (ivl[1 + j2] < tv) ? 1 : 0;
        int idx = p + 1;
        idx = idx < 1 ? 1 : idx;
        idx = idx > 32 ? 32 : idx;
        r_arr[t] = idx - 1;
        s_arr[t] = __fdiv_rn(1.0f, ivl[idx] - ivl[idx - 1]);
    }

    // biases along D rows (q*4+r) for this wave's stage1/2 n-tiles wv*2, wv*2+1
    f32x4 b1f[2], b2f[2];
#pragma unroll
    for (int tt = 0; tt < 2; tt++) {
        b1f[tt] = *(const f32x4*)(b1g + (wv * 2 + tt) * 16 + q * 4);
        b2f[tt] = *(const f32x4*)(b2g + (wv * 2 + tt) * 16 + q * 4);
    }

    // y0 = x0 @ Win.T + bin -> Y regs: Y[r] = y[m16][wv*16+q*4+r] (stage3 D layout)
    float Y[4], K1[4];
    {
        const float* xr = x0 + (row0 + m16) * 5;
        float xv[5];
#pragma unroll
        for (int d = 0; d < 5; d++) xv[d] = xr[d];
        int h0 = wv * 16 + q * 4;
        f16x4 hv, lv;
#pragma unroll
        for (int r = 0; r < 4; r++) {
            float acc = bin[h0 + r];
#pragma unroll
            for (int d = 0; d < 5; d++) acc += xv[d] * Win[(h0 + r) * 5 + d];
            Y[r] = acc;
            K1[r] = 0.f;
            _Float16 hi = (_Float16)acc;
            hv[r] = hi;
            lv[r] = (_Float16)(acc - (float)hi);
        }
        *(f16x4*)(P0h + m16 * AW + h0) = hv;   // 512 thr x 4 = full 16x128 coverage
        *(f16x4*)(P0l + m16 * AW + h0) = lv;
    }
    __syncthreads();

    // W1 fragment prefetch for eval 0: [tt][kc][plane] = 64 VGPRs
    f16x8 w1f[2][4][2];
#pragma unroll
    for (int tt = 0; tt < 2; tt++)
#pragma unroll
        for (int kc = 0; kc < 4; kc++) {
            const _Float16* bp = W1F + (((wv * 2 + tt) * 4 + kc) * 64 + lane) * 8;
            w1f[tt][kc][0] = *(const f16x8*)bp;
            w1f[tt][kc][1] = *(const f16x8*)(bp + 32768);
        }

    _Float16 *Aih = P0h, *Ail = P0l;    // in buffers
    _Float16 *Aoh = P1h, *Aol = P1l;    // out buffers

#pragma unroll 1
    for (int e = 0; e < 40; e++) {
        const int half = e & 1;
        const int ri   = r_arr[e];
        const float s  = s_arr[e];
        const _Float16* ABase = A3F + ri * 65536;

        // ---- stage1: h1 = relu(W1 . y), K=128; W1 frags preloaded ----
        // issue W2 window A (kc 0..3) first — in flight across all of stage1
        f16x8 w2a[2][4][2];
#pragma unroll
        for (int tt = 0; tt < 2; tt++)
#pragma unroll
            for (int kc = 0; kc < 4; kc++) {
                const _Float16* bp = W2F + (((wv * 2 + tt) * 8 + kc) * 64 + lane) * 8;
                w2a[tt][kc][0] = *(const f16x8*)bp;
                w2a[tt][kc][1] = *(const f16x8*)(bp + 65536);
            }
        f32x4 aA[2], aB[2], aC[2];
#pragma unroll
        for (int tt = 0; tt < 2; tt++) {
            aA[tt] = b1f[tt];
            aB[tt] = (f32x4){0.f, 0.f, 0.f, 0.f};
            aC[tt] = (f32x4){0.f, 0.f, 0.f, 0.f};
        }
#pragma unroll
        for (int kc = 0; kc < 4; kc++) {
            int ao = m16 * AW + kc * 32 + q * 8;
            f16x8 ah = *(const f16x8*)(Aih + ao);
            f16x8 al = *(const f16x8*)(Ail + ao);
#pragma unroll
            for (int tt = 0; tt < 2; tt++) {
                aA[tt] = __builtin_amdgcn_mfma_f32_16x16x32_f16(w1f[tt][kc][0], ah, aA[tt], 0, 0, 0);
                aB[tt] = __builtin_amdgcn_mfma_f32_16x16x32_f16(w1f[tt][kc][1], ah, aB[tt], 0, 0, 0);
                aC[tt] = __builtin_amdgcn_mfma_f32_16x16x32_f16(w1f[tt][kc][0], al, aC[tt], 0, 0, 0);
            }
        }
#pragma unroll
        for (int tt = 0; tt < 2; tt++) {        // commit h1 -> out, packed b64 hi/lo
            int n0 = (wv * 2 + tt) * 16 + q * 4;
            f16x4 hv, lv;
#pragma unroll
            for (int r = 0; r < 4; r++) {       // D: col=lane&15 (m), row=q*4+r (n)
                float v = fmaxf(aA[tt][r] + aB[tt][r] + aC[tt][r], 0.f);
                _Float16 hi = (_Float16)v;
                hv[r] = hi;
                lv[r] = (_Float16)(v - (float)hi);
            }
            *(f16x4*)(Aoh + m16 * AW + n0) = hv;
            *(f16x4*)(Aol + m16 * AW + n0) = lv;
        }
        bar_lds();

        // ---- stage2: h2 = tanh(W2 . h1), K=256 ----
#pragma unroll
        for (int tt = 0; tt < 2; tt++) {
            aA[tt] = b2f[tt];
            aB[tt] = (f32x4){0.f, 0.f, 0.f, 0.f};
            aC[tt] = (f32x4){0.f, 0.f, 0.f, 0.f};
        }
#pragma unroll
        for (int kc = 0; kc < 4; kc++) {        // first half with window A
            int ao = m16 * AW + kc * 32 + q * 8;
            f16x8 ah = *(const f16x8*)(Aoh + ao);
            f16x8 al = *(const f16x8*)(Aol + ao);
#pragma unroll
            for (int tt = 0; tt < 2; tt++) {
                aA[tt] = __builtin_amdgcn_mfma_f32_16x16x32_f16(w2a[tt][kc][0], ah, aA[tt], 0, 0, 0);
                aB[tt] = __builtin_amdgcn_mfma_f32_16x16x32_f16(w2a[tt][kc][1], ah, aB[tt], 0, 0, 0);
                aC[tt] = __builtin_amdgcn_mfma_f32_16x16x32_f16(w2a[tt][kc][0], al, aC[tt], 0, 0, 0);
            }
        }
        f16x8 w2b[2][4][2];                     // window B (kc 4..7)
#pragma unroll
        for (int tt = 0; tt < 2; tt++)
#pragma unroll
            for (int kc = 0; kc < 4; kc++) {
                const _Float16* bp = W2F + (((wv * 2 + tt) * 8 + 4 + kc) * 64 + lane) * 8;
                w2b[tt][kc][0] = *(const f16x8*)bp;
                w2b[tt][kc][1] = *(const f16x8*)(bp + 65536);
            }
#pragma unroll
        for (int kc = 0; kc < 4; kc++) {        // second half with window B
            int ao = m16 * AW + (4 + kc) * 32 + q * 8;
            f16x8 ah = *(const f16x8*)(Aoh + ao);
            f16x8 al = *(const f16x8*)(Aol + ao);
#pragma unroll
            for (int tt = 0; tt < 2; tt++) {
                aA[tt] = __builtin_amdgcn_mfma_f32_16x16x32_f16(w2b[tt][kc][0], ah, aA[tt], 0, 0, 0);
                aB[tt] = __builtin_amdgcn_mfma_f32_16x16x32_f16(w2b[tt][kc][1], ah, aB[tt], 0, 0, 0);
                aC[tt] = __builtin_amdgcn_mfma_f32_16x16x32_f16(w2b[tt][kc][0], al, aC[tt], 0, 0, 0);
            }
        }
        // issue A_r window A (kc 0..3; stage3 n-tile = wv) + c vector
        f16x8 a3a[4][2];
#pragma unroll
        for (int kc = 0; kc < 4; kc++) {
            const _Float16* bp = ABase + ((wv * 8 + kc) * 64 + lane) * 8;
            a3a[kc][0] = *(const f16x8*)bp;
            a3a[kc][1] = *(const f16x8*)(bp + 32768);
        }
        f32x4 cf = *(const f32x4*)(c_all + ri * 128 + wv * 16 + q * 4);
#pragma unroll
        for (int tt = 0; tt < 2; tt++) {        // commit h2 (tanh) -> in, packed b64
            int n0 = (wv * 2 + tt) * 16 + q * 4;
            f16x4 hv, lv;
#pragma unroll
            for (int r = 0; r < 4; r++) {
                float v = fast_tanh(aA[tt][r] + aB[tt][r] + aC[tt][r]);
                _Float16 hi = (_Float16)v;
                hv[r] = hi;
                lv[r] = (_Float16)(v - (float)hi);
            }
            *(f16x4*)(Aih + m16 * AW + n0) = hv;
            *(f16x4*)(Ail + m16 * AW + n0) = lv;
        }
        bar_lds();

        // ---- stage3: k = (A_r . h2 + c) * s; winB + next-eval W1 issued here ----
        f16x8 a3b[4][2];                        // kc 4..7
#pragma unroll
        for (int kc = 0; kc < 4; kc++) {
            const _Float16* bp = ABase + ((wv * 8 + 4 + kc) * 64 + lane) * 8;
            a3b[kc][0] = *(const f16x8*)bp;
            a3b[kc][1] = *(const f16x8*)(bp + 32768);
        }
#pragma unroll
        for (int tt = 0; tt < 2; tt++)          // next-eval W1 prefetch (fully hidden)
#pragma unroll
            for (int kc = 0; kc < 4; kc++) {
                const _Float16* bp = W1F + (((wv * 2 + tt) * 4 + kc) * 64 + lane) * 8;
                w1f[tt][kc][0] = *(const f16x8*)bp;
                w1f[tt][kc][1] = *(const f16x8*)(bp + 32768);
            }
        f32x4 kA = cf;
        f32x4 kB = (f32x4){0.f, 0.f, 0.f, 0.f};
        f32x4 kC = (f32x4){0.f, 0.f, 0.f, 0.f};
#pragma unroll
        for (int kc = 0; kc < 4; kc++) {        // kc 0..3 with a3a
            int ao = m16 * AW + kc * 32 + q * 8;
            f16x8 ah = *(const f16x8*)(Aih + ao);
            f16x8 al = *(const f16x8*)(Ail + ao);
            kA = __builtin_amdgcn_mfma_f32_16x16x32_f16(a3a[kc][0], ah, kA, 0, 0, 0);
            kB = __builtin_amdgcn_mfma_f32_16x16x32_f16(a3a[kc][1], ah, kB, 0, 0, 0);
            kC = __builtin_amdgcn_mfma_f32_16x16x32_f16(a3a[kc][0], al, kC, 0, 0, 0);
        }
#pragma unroll
        for (int kc = 0; kc < 4; kc++) {        // kc 4..7 with a3b
            int ao = m16 * AW + (4 + kc) * 32 + q * 8;
            f16x8 ah = *(const f16x8*)(Aih + ao);
            f16x8 al = *(const f16x8*)(Ail + ao);
            kA = __builtin_amdgcn_mfma_f32_16x16x32_f16(a3b[kc][0], ah, kA, 0, 0, 0);
            kB = __builtin_amdgcn_mfma_f32_16x16x32_f16(a3b[kc][1], ah, kB, 0, 0, 0);
            kC = __builtin_amdgcn_mfma_f32_16x16x32_f16(a3b[kc][0], al, kC, 0, 0, 0);
        }
        {                                       // Heun commit + y -> out, packed b64
            int h0 = wv * 16 + q * 4;
            f16x4 hv, lv;
#pragma unroll
            for (int r = 0; r < 4; r++) {
                float kv = (kA[r] + kB[r] + kC[r]) * s;
                float yn;
                if (half == 0) {                 // k1: stash, form y+dt*k1
                    K1[r] = kv;
                    yn = Y[r] + dt * kv;
                } else {                         // k2: y += 0.5*dt*(k1+k2)
                    yn = Y[r] + 0.5f * dt * (K1[r] + kv);
                    Y[r] = yn;
                }
                _Float16 hi = (_Float16)yn;
                hv[r] = hi;
                lv[r] = (_Float16)(yn - (float)hi);
            }
            *(f16x4*)(Aoh + m16 * AW + h0) = hv;
            *(f16x4*)(Aol + m16 * AW + h0) = lv;
        }
        bar_lds();
        _Float16* tp;
        tp = Aih; Aih = Aoh; Aoh = tp;
        tp = Ail; Ail = Aol; Aol = tp;
    }

    // epilogue: Y regs -> Ys f32 [m][h]
#pragma unroll
    for (int r = 0; r < 4; r++)
        Ys[m16 * YW + wv * 16 + q * 4 + r] = Y[r];
    __syncthreads();
    if (t < 160) {                  // logits
        int m = t / 10, c = t % 10;
        float acc = bout[c];
        for (int k = 0; k < 128; k++) acc += Ys[m * YW + k] * Wout[c * 128 + k];
        lg[m][c] = acc;
    }
    __syncthreads();
    if (t < 16) {                   // softmax
        float mx = -1e30f;
#pragma unroll
        for (int c = 0; c < 10; c++) mx = fmaxf(mx, lg[t][c]);
        float ex[10], sum = 0.f;
#pragma unroll
        for (int c = 0; c < 10; c++) { ex[c] = expf(lg[t][c] - mx); sum += ex[c]; }
        float inv = __fdiv_rn(1.0f, sum);
#pragma unroll
        for (int c = 0; c < 10; c++) out[(row0 + t) * 10 + c] = ex[c] * inv;
    }
}

extern "C" void kernel_launch(void* const* d_in, const int* in_sizes, int n_in,
                              void* d_out, int out_size, void* d_ws, size_t ws_size,
                              hipStream_t stream) {
    const float* ts     = (const float*)d_in[0];
    const float* logsig = (const float*)d_in[1];
    const float* x0     = (const float*)d_in[2];
    const float* ivls   = (const float*)d_in[3];
    const float* Wvf1   = (const float*)d_in[4];
    const float* bvf1   = (const float*)d_in[5];
    const float* Wvf2   = (const float*)d_in[6];
    const float* bvf2   = (const float*)d_in[7];
    const float* Wm     = (const float*)d_in[8];
    const float* bm     = (const float*)d_in[9];
    const float* Win    = (const float*)d_in[10];
    const float* bin    = (const float*)d_in[11];
    const float* Wout   = (const float*)d_in[12];
    const float* bout   = (const float*)d_in[13];

    _Float16* W1F = (_Float16*)d_ws;            // 65536 halfs (128KB, hi+lo)
    _Float16* W2F = W1F + 65536;                // 131072 halfs (256KB, hi+lo)
    _Float16* A3F = W2F + 131072;               // 32*65536 halfs (4MB, hi+lo per r)
    float* c_all = (float*)(A3F + 32 * 65536);  // 4096 f32 (16KB)
    float* out = (float*)d_out;

    pk_all<<<dim3(464), dim3(256), 0, stream>>>(Wvf1, Wvf2, Wm, bm, logsig,
                                                W1F, W2F, A3F, c_all);
    rde_main<<<dim3(32), dim3(512), 0, stream>>>(
        ts, x0, ivls, bvf1, bvf2, Win, bin, Wout, bout,
        W1F, W2F, A3F, c_all, out);
}